// Round 3
// baseline (848.926 us; speedup 1.0000x reference)
//
#include <hip/hip_runtime.h>

// ---------------- types ----------------
typedef __attribute__((ext_vector_type(8))) short short8;
typedef __attribute__((ext_vector_type(4))) float f32x4;
typedef __attribute__((ext_vector_type(4))) unsigned short u16x4;

static __device__ __forceinline__ unsigned short f2bf(float x) {
  union { float f; unsigned u; } v; v.f = x;
  unsigned r = v.u + 0x7fffu + ((v.u >> 16) & 1u);   // round-to-nearest-even
  return (unsigned short)(r >> 16);
}
static __device__ __forceinline__ float bf2f(unsigned short h) {
  union { unsigned u; float f; } v; v.u = ((unsigned)h) << 16;
  return v.f;
}

// async global->LDS, 16B per lane (linear LDS dest = wave base + lane*16)
static __device__ __forceinline__ void gl_lds16(const void* g, void* s) {
  __builtin_amdgcn_global_load_lds(
      (const __attribute__((address_space(1))) void*)g,
      (__attribute__((address_space(3))) void*)s, 16, 0, 0);
}

// ---------------- fp32 -> bf16 (4 elems/thread) ----------------
__global__ __launch_bounds__(256) void to_bf16(const float* __restrict__ src,
                                               unsigned short* __restrict__ dst, int n4) {
  int i = blockIdx.x * blockDim.x + threadIdx.x;
  int stride = gridDim.x * blockDim.x;
  for (; i < n4; i += stride) {
    float4 x = *(const float4*)&src[i * 4];
    u16x4 o;
    o.x = f2bf(x.x); o.y = f2bf(x.y); o.z = f2bf(x.z); o.w = f2bf(x.w);
    *(u16x4*)&dst[i * 4] = o;
  }
}

// fp32 [rows][1024] -> bf16 [rows][3072].
// bmode 0: [hi | lo | hi] (A side)   bmode 1: [hi | hi | lo] (B side)
__global__ __launch_bounds__(256) void split3_bf16(const float* __restrict__ src,
                                                   unsigned short* __restrict__ dst,
                                                   int n, int bmode) {
  int i = blockIdx.x * blockDim.x + threadIdx.x;
  int stride = gridDim.x * blockDim.x;
  for (; i < n; i += stride) {
    int r = i >> 10, c = i & 1023;
    float x = src[i];
    unsigned short hi = f2bf(x);
    unsigned short lo = f2bf(x - bf2f(hi));
    unsigned short* row = dst + (size_t)r * 3072;
    if (bmode == 0) { row[c] = hi; row[1024 + c] = lo; row[2048 + c] = hi; }
    else            { row[c] = hi; row[1024 + c] = hi; row[2048 + c] = lo; }
  }
}

// ---------------- bf16 MFMA GEMM (double-buffered, global_load_lds) ----------------
// C[m][n] = sum_k A[m][k] * Bw[n][k] + bias[n]
// A: [4096][lda] bf16 (row-major, K-major), Bw: [1024][ldb] bf16 (N rows, K-major)
// mode 0: store permuted to [b][h][l][d] fp32 (b=m>>9, l=m&511, h=n>>6, d=n&63)
// mode 1: store plain [m][1024 + n]
__global__ __launch_bounds__(256) void gemm_bf16(const unsigned short* __restrict__ A, int lda,
                                                 const unsigned short* __restrict__ Bw, int ldb,
                                                 const float* __restrict__ bias,
                                                 float* __restrict__ Cout, int K, int mode) {
  __shared__ unsigned short As[2][128 * 32];
  __shared__ unsigned short Bs[2][128 * 32];
  const int t = threadIdx.x;
  const int lane = t & 63;
  const int w = t >> 6;
  const int wr = w >> 1, wc = w & 1;
  const int mt = blockIdx.x >> 3, nt = blockIdx.x & 7;
  const int m0 = mt * 128, n0 = nt * 128;
  const int r16 = lane & 15, kb = lane >> 4;   // kb in 0..3

  f32x4 acc[4][4];
#pragma unroll
  for (int mi = 0; mi < 4; ++mi)
#pragma unroll
    for (int ni = 0; ni < 4; ++ni) acc[mi][ni] = (f32x4){0.f, 0.f, 0.f, 0.f};

  auto STAGE = [&](int buf, int k0) {
#pragma unroll
    for (int i = 0; i < 2; ++i) {
      int c = i * 256 + t;                 // 512 chunks of 8 bf16 (16 B), linear in lane
      int row = c >> 2, kc = (c & 3) * 8;
      gl_lds16(&A[(size_t)(m0 + row) * lda + k0 + kc], &As[buf][c * 8]);
      gl_lds16(&Bw[(size_t)(n0 + row) * ldb + k0 + kc], &Bs[buf][c * 8]);
    }
  };

  const int NT = K / 32;
  STAGE(0, 0);
  __syncthreads();
  int cur = 0;
  for (int kt = 0; kt < NT; ++kt) {
    if (kt + 1 < NT) STAGE(cur ^ 1, (kt + 1) * 32);
    short8 af[4], bf[4];
#pragma unroll
    for (int mi = 0; mi < 4; ++mi)
      af[mi] = *(const short8*)&As[cur][(wr * 64 + mi * 16 + r16) * 32 + kb * 8];
#pragma unroll
    for (int ni = 0; ni < 4; ++ni)
      bf[ni] = *(const short8*)&Bs[cur][(wc * 64 + ni * 16 + r16) * 32 + kb * 8];
#pragma unroll
    for (int mi = 0; mi < 4; ++mi)
#pragma unroll
      for (int ni = 0; ni < 4; ++ni)
        acc[mi][ni] = __builtin_amdgcn_mfma_f32_16x16x32_bf16(af[mi], bf[ni], acc[mi][ni], 0, 0, 0);
    __syncthreads();
    cur ^= 1;
  }

  const int rowD = (lane >> 4) * 4;
#pragma unroll
  for (int mi = 0; mi < 4; ++mi) {
#pragma unroll
    for (int ni = 0; ni < 4; ++ni) {
      int n = n0 + wc * 64 + ni * 16 + (lane & 15);
      float bv = bias[n];
#pragma unroll
      for (int j = 0; j < 4; ++j) {
        int m = m0 + wr * 64 + mi * 16 + rowD + j;
        float val = acc[mi][ni][j] + bv;
        if (mode == 0) {
          int b = m >> 9, l = m & 511, h = n >> 6, d = n & 63;
          Cout[(((size_t)(b * 16 + h)) * 512 + l) * 64 + d] = val;
        } else {
          Cout[(size_t)m * 1024 + n] = val;
        }
      }
    }
  }
}

// ---------------- fused attention (fp32) ----------------
// grid: 16 h * 64 l-tiles = 1024 wgs, 256 threads
// per wg: 8 query rows (l0..l0+7), all 8 batches; online softmax over r in tiles of 32.
// Epilogue writes hi/lo/hi bf16 split directly into Abig [4096][3072].
__global__ __launch_bounds__(256) void attn_kernel(const float* __restrict__ qh,
                                                   const float* __restrict__ kh,
                                                   const float* __restrict__ vh,
                                                   const float* __restrict__ rel,
                                                   const int* __restrict__ mask,
                                                   unsigned short* __restrict__ Abig) {
  __shared__ float qs[8][8][64];   // [b][l][d]
  __shared__ float sp[8][8][33];   // [b][l][rr] scores then p (padded: bank-conflict-free)
  __shared__ float sstS[8][8], osc[8][8];
  const int t = threadIdx.x;
  const int h = blockIdx.x >> 6;
  const int l0 = (blockIdx.x & 63) * 8;

  // load q rows for all batches
#pragma unroll
  for (int i = 0; i < 4; ++i) {
    int f = i * 256 + t;                       // 1024 float4 chunks
    int b = f >> 7, l = (f >> 4) & 7, d4 = (f & 15) * 4;
    *(float4*)&qs[b][l][d4] =
        *(const float4*)&qh[(((size_t)(b * 16 + h)) * 512 + (l0 + l)) * 64 + d4];
  }

  float oacc[8][2];
#pragma unroll
  for (int l = 0; l < 8; ++l) { oacc[l][0] = 0.f; oacc[l][1] = 0.f; }

  const int bA = t >> 5;       // batch for passes A/D
  const int rr = t & 31;       // r within tile for passes A/B
  const int lB = t >> 5;       // l for pass B
  const int dp = t & 31;       // d-pair for pass D
  // pass C mapping: 4 lanes per (b,l) row
  const int gC = t >> 2;               // 0..63 -> (b,l)
  const int bC = gC >> 3, lC = gC & 7;
  const int qq = t & 3;                // quarter: elements qq*8..qq*8+7
  float m_run = -1e30f, s_run = 0.f;   // online softmax state (replicated x4)

  for (int r0 = 0; r0 < 512; r0 += 32) {
    __syncthreads();
    // ---- pass A: QK^T * scale ----
    {
      int r = r0 + rr;
      const float* kp = &kh[(((size_t)(bA * 16 + h)) * 512 + r) * 64];
      float accs[8] = {0, 0, 0, 0, 0, 0, 0, 0};
      for (int d0 = 0; d0 < 64; d0 += 4) {
        float4 kv = *(const float4*)&kp[d0];
#pragma unroll
        for (int l = 0; l < 8; ++l) {
          float4 qv = *(const float4*)&qs[bA][l][d0];
          accs[l] = fmaf(qv.x, kv.x, accs[l]);
          accs[l] = fmaf(qv.y, kv.y, accs[l]);
          accs[l] = fmaf(qv.z, kv.z, accs[l]);
          accs[l] = fmaf(qv.w, kv.w, accs[l]);
        }
      }
#pragma unroll
      for (int l = 0; l < 8; ++l) sp[bA][l][rr] = accs[l] * 0.125f;
    }
    __syncthreads();
    // ---- pass B: + q . rel (streams the 1 GiB rel tensor exactly once) ----
    {
      int r = r0 + rr;
      const float* rp = &rel[((size_t)(l0 + lB) * 512 + r) * 1024 + h * 64];
      float accg[8] = {0, 0, 0, 0, 0, 0, 0, 0};
      for (int d0 = 0; d0 < 64; d0 += 4) {
        float4 rv = *(const float4*)&rp[d0];
#pragma unroll
        for (int b = 0; b < 8; ++b) {
          float4 qv = *(const float4*)&qs[b][lB][d0];
          accg[b] = fmaf(qv.x, rv.x, accg[b]);
          accg[b] = fmaf(qv.y, rv.y, accg[b]);
          accg[b] = fmaf(qv.z, rv.z, accg[b]);
          accg[b] = fmaf(qv.w, rv.w, accg[b]);
        }
      }
#pragma unroll
      for (int b = 0; b < 8; ++b) sp[b][lB][rr] += accg[b];
    }
    __syncthreads();
    // ---- pass C: mask + online softmax (all 256 threads; 4-lane-group reduce) ----
    {
      const int* mp = &mask[(size_t)(l0 + lC) * 512 + r0];
      float vals[8];
      float mt = -1e30f;
#pragma unroll
      for (int j = 0; j < 8; ++j) {
        int i = qq * 8 + j;
        float vsc = sp[bC][lC][i];
        if (mp[i] == 0) vsc = -1e9f;
        vals[j] = vsc;
        mt = fmaxf(mt, vsc);
      }
      mt = fmaxf(mt, __shfl_xor(mt, 1));
      mt = fmaxf(mt, __shfl_xor(mt, 2));
      float mn = fmaxf(m_run, mt);
      float f = __expf(m_run - mn);
      float ps = 0.f;
#pragma unroll
      for (int j = 0; j < 8; ++j) {
        float p = __expf(vals[j] - mn);
        sp[bC][lC][qq * 8 + j] = p;
        ps += p;
      }
      ps += __shfl_xor(ps, 1);
      ps += __shfl_xor(ps, 2);
      s_run = s_run * f + ps;
      m_run = mn;
      if (qq == 0) osc[bC][lC] = f;
    }
    __syncthreads();
    // ---- pass D: rescale + PV ----
    {
#pragma unroll
      for (int l = 0; l < 8; ++l) {
        float f = osc[bA][l];
        oacc[l][0] *= f; oacc[l][1] *= f;
      }
      const float* vp = &vh[(((size_t)(bA * 16 + h)) * 512 + r0) * 64 + dp * 2];
      for (int i = 0; i < 32; ++i) {
        float2 vv = *(const float2*)&vp[(size_t)i * 64];
#pragma unroll
        for (int l = 0; l < 8; ++l) {
          float p = sp[bA][l][i];
          oacc[l][0] = fmaf(p, vv.x, oacc[l][0]);
          oacc[l][1] = fmaf(p, vv.y, oacc[l][1]);
        }
      }
    }
  }
  // publish softmax sums
  if (qq == 0) sstS[bC][lC] = s_run;
  __syncthreads();
  // ---- finalize: divide by sum; write hi/lo/hi bf16 split into Abig [m][3072] ----
#pragma unroll
  for (int l = 0; l < 8; ++l) {
    float inv = 1.0f / sstS[bA][l];
    float ox = oacc[l][0] * inv;
    float oy = oacc[l][1] * inv;
    unsigned short hx = f2bf(ox), hy = f2bf(oy);
    unsigned short lx = f2bf(ox - bf2f(hx)), ly = f2bf(oy - bf2f(hy));
    unsigned short* rowp = Abig + (size_t)(bA * 512 + l0 + l) * 3072;
    int c = h * 64 + dp * 2;
    *(ushort2*)&rowp[c]        = make_ushort2(hx, hy);
    *(ushort2*)&rowp[1024 + c] = make_ushort2(lx, ly);
    *(ushort2*)&rowp[2048 + c] = make_ushort2(hx, hy);
  }
}

// ---------------- launcher ----------------
extern "C" void kernel_launch(void* const* d_in, const int* in_sizes, int n_in,
                              void* d_out, int out_size, void* d_ws, size_t ws_size,
                              hipStream_t stream) {
  const float* q    = (const float*)d_in[0];
  const float* k    = (const float*)d_in[1];
  const float* v    = (const float*)d_in[2];
  const float* rel  = (const float*)d_in[3];
  const int*   mask = (const int*)d_in[4];
  const float* Wq   = (const float*)d_in[5];
  const float* bq   = (const float*)d_in[6];
  const float* Wk   = (const float*)d_in[7];
  const float* bk   = (const float*)d_in[8];
  const float* Wv   = (const float*)d_in[9];
  const float* bv   = (const float*)d_in[10];
  const float* Wo   = (const float*)d_in[11];
  const float* bo   = (const float*)d_in[12];
  float* out = (float*)d_out;

  char* ws = (char*)d_ws;
  const size_t SZ_BHLD = (size_t)8 * 16 * 512 * 64 * 4;   // 16.78 MB each
  float* qh = (float*)(ws);
  float* kh = (float*)(ws + SZ_BHLD);
  float* vh = (float*)(ws + 2 * SZ_BHLD);
  // X region (25.17 MB): qbf/kbf/vbf during projections, then Abig [4096][3072]
  unsigned short* X = (unsigned short*)(ws + 3 * SZ_BHLD);
  // Y region (6.29 MB): Wq/Wk/Wv bf16 during projections, then Wo split [1024][3072]
  unsigned short* Y = (unsigned short*)(ws + 3 * SZ_BHLD + 25165824);
  unsigned short* qbf = X;
  unsigned short* kbf = X + 4194304;
  unsigned short* vbf = X + 8388608;
  unsigned short* Wqb = Y;
  unsigned short* Wkb = Y + 1048576;
  unsigned short* Wvb = Y + 2097152;

  // 1) convert inputs + weights to bf16 (4 elems/thread)
  to_bf16<<<1024, 256, 0, stream>>>(q, qbf, 1048576);
  to_bf16<<<1024, 256, 0, stream>>>(k, kbf, 1048576);
  to_bf16<<<1024, 256, 0, stream>>>(v, vbf, 1048576);
  to_bf16<<<256, 256, 0, stream>>>(Wq, Wqb, 262144);
  to_bf16<<<256, 256, 0, stream>>>(Wk, Wkb, 262144);
  to_bf16<<<256, 256, 0, stream>>>(Wv, Wvb, 262144);

  // 2) QKV projections -> [b][h][l][d] fp32
  gemm_bf16<<<256, 256, 0, stream>>>(qbf, 1024, Wqb, 1024, bq, qh, 1024, 0);
  gemm_bf16<<<256, 256, 0, stream>>>(kbf, 1024, Wkb, 1024, bk, kh, 1024, 0);
  gemm_bf16<<<256, 256, 0, stream>>>(vbf, 1024, Wvb, 1024, bv, vh, 1024, 0);

  // 3) Wo hi|hi|lo split into Y (overwrites dead Wq/Wk/Wv bf16)
  split3_bf16<<<1024, 256, 0, stream>>>(Wo, Y, 1048576, 1);

  // 4) fused attention (fp32, streams rel once); writes hi|lo|hi split into X
  attn_kernel<<<1024, 256, 0, stream>>>(qh, kh, vh, rel, mask, X);

  // 5) output projection, K=3072 split-GEMM -> d_out [4096][1024]
  gemm_bf16<<<256, 256, 0, stream>>>(X, 3072, Y, 3072, bo, out, 3072, 1);
}

// Round 4
// 661.576 us; speedup vs baseline: 1.2832x; 1.2832x over previous
//
#include <hip/hip_runtime.h>

// ---------------- types ----------------
typedef __attribute__((ext_vector_type(8))) short short8;
typedef __attribute__((ext_vector_type(4))) float f32x4;
typedef __attribute__((ext_vector_type(4))) unsigned short u16x4;

static __device__ __forceinline__ unsigned short f2bf(float x) {
  union { float f; unsigned u; } v; v.f = x;
  unsigned r = v.u + 0x7fffu + ((v.u >> 16) & 1u);   // round-to-nearest-even
  return (unsigned short)(r >> 16);
}
static __device__ __forceinline__ float bf2f(unsigned short h) {
  union { unsigned u; float f; } v; v.u = ((unsigned)h) << 16;
  return v.f;
}

// async global->LDS, 16B per lane (linear LDS dest = wave base + lane*16)
static __device__ __forceinline__ void gl_lds16(const void* g, void* s) {
  __builtin_amdgcn_global_load_lds(
      (const __attribute__((address_space(1))) void*)g,
      (__attribute__((address_space(3))) void*)s, 16, 0, 0);
}

// ---------------- fp32 -> bf16 (4 elems/thread) ----------------
__global__ __launch_bounds__(256) void to_bf16(const float* __restrict__ src,
                                               unsigned short* __restrict__ dst, int n4) {
  int i = blockIdx.x * blockDim.x + threadIdx.x;
  int stride = gridDim.x * blockDim.x;
  for (; i < n4; i += stride) {
    float4 x = *(const float4*)&src[i * 4];
    u16x4 o;
    o.x = f2bf(x.x); o.y = f2bf(x.y); o.z = f2bf(x.z); o.w = f2bf(x.w);
    *(u16x4*)&dst[i * 4] = o;
  }
}

// fp32 [rows][1024] -> bf16 [rows][3072].
// bmode 0: [hi | lo | hi] (A side)   bmode 1: [hi | hi | lo] (B side)
__global__ __launch_bounds__(256) void split3_bf16(const float* __restrict__ src,
                                                   unsigned short* __restrict__ dst,
                                                   int n, int bmode) {
  int i = blockIdx.x * blockDim.x + threadIdx.x;
  int stride = gridDim.x * blockDim.x;
  for (; i < n; i += stride) {
    int r = i >> 10, c = i & 1023;
    float x = src[i];
    unsigned short hi = f2bf(x);
    unsigned short lo = f2bf(x - bf2f(hi));
    unsigned short* row = dst + (size_t)r * 3072;
    if (bmode == 0) { row[c] = hi; row[1024 + c] = lo; row[2048 + c] = hi; }
    else            { row[c] = hi; row[1024 + c] = hi; row[2048 + c] = lo; }
  }
}

// ---------------- bf16 MFMA GEMM (double-buffered, global_load_lds) ----------------
// C[m][n] = sum_k A[m][k] * Bw[n][k] + bias[n]
// mode 0: store permuted to [b][h][l][d] fp32; mode 1: store plain [m][1024+n]
__global__ __launch_bounds__(256) void gemm_bf16(const unsigned short* __restrict__ A, int lda,
                                                 const unsigned short* __restrict__ Bw, int ldb,
                                                 const float* __restrict__ bias,
                                                 float* __restrict__ Cout, int K, int mode) {
  __shared__ unsigned short As[2][128 * 32];
  __shared__ unsigned short Bs[2][128 * 32];
  const int t = threadIdx.x;
  const int lane = t & 63;
  const int w = t >> 6;
  const int wr = w >> 1, wc = w & 1;
  const int mt = blockIdx.x >> 3, nt = blockIdx.x & 7;
  const int m0 = mt * 128, n0 = nt * 128;
  const int r16 = lane & 15, kb = lane >> 4;

  f32x4 acc[4][4];
#pragma unroll
  for (int mi = 0; mi < 4; ++mi)
#pragma unroll
    for (int ni = 0; ni < 4; ++ni) acc[mi][ni] = (f32x4){0.f, 0.f, 0.f, 0.f};

  auto STAGE = [&](int buf, int k0) {
#pragma unroll
    for (int i = 0; i < 2; ++i) {
      int c = i * 256 + t;
      int row = c >> 2, kc = (c & 3) * 8;
      gl_lds16(&A[(size_t)(m0 + row) * lda + k0 + kc], &As[buf][c * 8]);
      gl_lds16(&Bw[(size_t)(n0 + row) * ldb + k0 + kc], &Bs[buf][c * 8]);
    }
  };

  const int NT = K / 32;
  STAGE(0, 0);
  __syncthreads();
  int cur = 0;
  for (int kt = 0; kt < NT; ++kt) {
    if (kt + 1 < NT) STAGE(cur ^ 1, (kt + 1) * 32);
    short8 af[4], bf[4];
#pragma unroll
    for (int mi = 0; mi < 4; ++mi)
      af[mi] = *(const short8*)&As[cur][(wr * 64 + mi * 16 + r16) * 32 + kb * 8];
#pragma unroll
    for (int ni = 0; ni < 4; ++ni)
      bf[ni] = *(const short8*)&Bs[cur][(wc * 64 + ni * 16 + r16) * 32 + kb * 8];
#pragma unroll
    for (int mi = 0; mi < 4; ++mi)
#pragma unroll
      for (int ni = 0; ni < 4; ++ni)
        acc[mi][ni] = __builtin_amdgcn_mfma_f32_16x16x32_bf16(af[mi], bf[ni], acc[mi][ni], 0, 0, 0);
    __syncthreads();
    cur ^= 1;
  }

  const int rowD = (lane >> 4) * 4;
#pragma unroll
  for (int mi = 0; mi < 4; ++mi) {
#pragma unroll
    for (int ni = 0; ni < 4; ++ni) {
      int n = n0 + wc * 64 + ni * 16 + (lane & 15);
      float bv = bias[n];
#pragma unroll
      for (int j = 0; j < 4; ++j) {
        int m = m0 + wr * 64 + mi * 16 + rowD + j;
        float val = acc[mi][ni][j] + bv;
        if (mode == 0) {
          int b = m >> 9, l = m & 511, h = n >> 6, d = n & 63;
          Cout[(((size_t)(b * 16 + h)) * 512 + l) * 64 + d] = val;
        } else {
          Cout[(size_t)m * 1024 + n] = val;
        }
      }
    }
  }
}

// ---------------- fused attention (fp32, rel register-prefetch) ----------------
// grid: 1024 wgs, XCD-swizzled -> (h, l0). per wg: 8 q-rows, all 8 batches.
__global__ __launch_bounds__(256) void attn_kernel(const float* __restrict__ qh,
                                                   const float* __restrict__ kh,
                                                   const float* __restrict__ vh,
                                                   const float* __restrict__ rel,
                                                   const int* __restrict__ mask,
                                                   unsigned short* __restrict__ Abig) {
  __shared__ float qs[8][8][64];   // [b][l][d]
  __shared__ float sp[8][8][36];   // QK scores, then p (pad 36: 16B-aligned rows)
  __shared__ float sp2[8][8][36];  // rel scores
  __shared__ float sstS[8][8], osc[8][8];
  const int t = threadIdx.x;
  // XCD swizzle: consecutive bids round-robin XCDs; pin each head to one XCD.
  const int bid = blockIdx.x;
  const int slot = bid & 7;
  const int grp = bid >> 3;            // 0..127
  const int h = slot * 2 + (grp & 1);  // heads {2s, 2s+1} on XCD s
  const int l0 = (grp >> 1) * 8;       // 0..63 tiles

  // load q rows for all batches
#pragma unroll
  for (int i = 0; i < 4; ++i) {
    int f = i * 256 + t;
    int b = f >> 7, l = (f >> 4) & 7, d4 = (f & 15) * 4;
    *(float4*)&qs[b][l][d4] =
        *(const float4*)&qh[(((size_t)(b * 16 + h)) * 512 + (l0 + l)) * 64 + d4];
  }

  float oacc[8][2];
#pragma unroll
  for (int l = 0; l < 8; ++l) { oacc[l][0] = 0.f; oacc[l][1] = 0.f; }

  const int bA = t >> 5;       // batch for passes A/D
  const int rr = t & 31;       // r within tile (passes A/B)
  const int lB = t >> 5;       // l for pass B
  const int dp = t & 31;       // d-pair for pass D
  const int gC = t >> 2;       // pass C: 4 lanes per (b,l)
  const int bC = gC >> 3, lC = gC & 7;
  const int qq = t & 3;
  float m_run = -1e30f, s_run = 0.f;

  // rel prefetch: this thread owns row (l0+lB, r0+rr), 64 floats
  const float* relbase = &rel[(size_t)(l0 + lB) * 512 * 1024 + h * 64];
  float4 R[16];
#pragma unroll
  for (int j = 0; j < 16; ++j)
    R[j] = *(const float4*)&relbase[(size_t)rr * 1024 + j * 4];

  __syncthreads();

  for (int r0 = 0; r0 < 512; r0 += 32) {
    // ---- pass A: QK^T * scale -> sp ----
    {
      int r = r0 + rr;
      const float* kp = &kh[(((size_t)(bA * 16 + h)) * 512 + r) * 64];
      float accs[8] = {0, 0, 0, 0, 0, 0, 0, 0};
#pragma unroll
      for (int d0 = 0; d0 < 16; ++d0) {
        float4 kv = *(const float4*)&kp[d0 * 4];
#pragma unroll
        for (int l = 0; l < 8; ++l) {
          float4 qv = *(const float4*)&qs[bA][l][d0 * 4];
          accs[l] = fmaf(qv.x, kv.x, accs[l]);
          accs[l] = fmaf(qv.y, kv.y, accs[l]);
          accs[l] = fmaf(qv.z, kv.z, accs[l]);
          accs[l] = fmaf(qv.w, kv.w, accs[l]);
        }
      }
#pragma unroll
      for (int l = 0; l < 8; ++l) sp[bA][l][rr] = accs[l] * 0.125f;
    }
    // ---- pass B: q . rel from prefetched regs -> sp2; then issue next tile ----
    {
      float accg[8] = {0, 0, 0, 0, 0, 0, 0, 0};
#pragma unroll
      for (int j = 0; j < 16; ++j) {
        float4 rv = R[j];
#pragma unroll
        for (int b = 0; b < 8; ++b) {
          float4 qv = *(const float4*)&qs[b][lB][j * 4];
          accg[b] = fmaf(qv.x, rv.x, accg[b]);
          accg[b] = fmaf(qv.y, rv.y, accg[b]);
          accg[b] = fmaf(qv.z, rv.z, accg[b]);
          accg[b] = fmaf(qv.w, rv.w, accg[b]);
        }
      }
#pragma unroll
      for (int b = 0; b < 8; ++b) sp2[b][lB][rr] = accg[b];
      if (r0 + 32 < 512) {
        const float* rp = relbase + (size_t)(r0 + 32 + rr) * 1024;
#pragma unroll
        for (int j = 0; j < 16; ++j) R[j] = *(const float4*)&rp[j * 4];
      }
    }
    __syncthreads();
    // ---- pass C: mask + online softmax (all 256 threads; 4-lane groups) ----
    {
      const int* mp = &mask[(size_t)(l0 + lC) * 512 + r0];
      float4 a0 = *(const float4*)&sp[bC][lC][qq * 8];
      float4 a1 = *(const float4*)&sp[bC][lC][qq * 8 + 4];
      float4 b0 = *(const float4*)&sp2[bC][lC][qq * 8];
      float4 b1 = *(const float4*)&sp2[bC][lC][qq * 8 + 4];
      float vals[8] = {a0.x + b0.x, a0.y + b0.y, a0.z + b0.z, a0.w + b0.w,
                       a1.x + b1.x, a1.y + b1.y, a1.z + b1.z, a1.w + b1.w};
      float mt = -1e30f;
#pragma unroll
      for (int j = 0; j < 8; ++j) {
        if (mp[qq * 8 + j] == 0) vals[j] = -1e9f;
        mt = fmaxf(mt, vals[j]);
      }
      mt = fmaxf(mt, __shfl_xor(mt, 1));
      mt = fmaxf(mt, __shfl_xor(mt, 2));
      float mn = fmaxf(m_run, mt);
      float f = __expf(m_run - mn);
      float ps = 0.f;
      float p[8];
#pragma unroll
      for (int j = 0; j < 8; ++j) { p[j] = __expf(vals[j] - mn); ps += p[j]; }
      *(float4*)&sp[bC][lC][qq * 8]     = make_float4(p[0], p[1], p[2], p[3]);
      *(float4*)&sp[bC][lC][qq * 8 + 4] = make_float4(p[4], p[5], p[6], p[7]);
      ps += __shfl_xor(ps, 1);
      ps += __shfl_xor(ps, 2);
      s_run = s_run * f + ps;
      m_run = mn;
      if (qq == 0) osc[bC][lC] = f;
    }
    __syncthreads();
    // ---- pass D: rescale + PV ----
    {
#pragma unroll
      for (int l = 0; l < 8; ++l) {
        float f = osc[bA][l];
        oacc[l][0] *= f; oacc[l][1] *= f;
      }
      const float* vp = &vh[(((size_t)(bA * 16 + h)) * 512 + r0) * 64 + dp * 2];
#pragma unroll
      for (int i0 = 0; i0 < 8; ++i0) {
        float2 v0 = *(const float2*)&vp[(size_t)(i0 * 4 + 0) * 64];
        float2 v1 = *(const float2*)&vp[(size_t)(i0 * 4 + 1) * 64];
        float2 v2 = *(const float2*)&vp[(size_t)(i0 * 4 + 2) * 64];
        float2 v3 = *(const float2*)&vp[(size_t)(i0 * 4 + 3) * 64];
#pragma unroll
        for (int l = 0; l < 8; ++l) {
          float4 p4 = *(const float4*)&sp[bA][l][i0 * 4];
          oacc[l][0] = fmaf(p4.x, v0.x, oacc[l][0]);
          oacc[l][1] = fmaf(p4.x, v0.y, oacc[l][1]);
          oacc[l][0] = fmaf(p4.y, v1.x, oacc[l][0]);
          oacc[l][1] = fmaf(p4.y, v1.y, oacc[l][1]);
          oacc[l][0] = fmaf(p4.z, v2.x, oacc[l][0]);
          oacc[l][1] = fmaf(p4.z, v2.y, oacc[l][1]);
          oacc[l][0] = fmaf(p4.w, v3.x, oacc[l][0]);
          oacc[l][1] = fmaf(p4.w, v3.y, oacc[l][1]);
        }
      }
    }
    __syncthreads();
  }
  // publish softmax sums
  if (qq == 0) sstS[bC][lC] = s_run;
  __syncthreads();
  // ---- finalize: divide by sum; write hi/lo/hi bf16 split into Abig [m][3072] ----
#pragma unroll
  for (int l = 0; l < 8; ++l) {
    float inv = 1.0f / sstS[bA][l];
    float ox = oacc[l][0] * inv;
    float oy = oacc[l][1] * inv;
    unsigned short hx = f2bf(ox), hy = f2bf(oy);
    unsigned short lx = f2bf(ox - bf2f(hx)), ly = f2bf(oy - bf2f(hy));
    unsigned short* rowp = Abig + (size_t)(bA * 512 + l0 + l) * 3072;
    int c = h * 64 + dp * 2;
    *(ushort2*)&rowp[c]        = make_ushort2(hx, hy);
    *(ushort2*)&rowp[1024 + c] = make_ushort2(lx, ly);
    *(ushort2*)&rowp[2048 + c] = make_ushort2(hx, hy);
  }
}

// ---------------- launcher ----------------
extern "C" void kernel_launch(void* const* d_in, const int* in_sizes, int n_in,
                              void* d_out, int out_size, void* d_ws, size_t ws_size,
                              hipStream_t stream) {
  const float* q    = (const float*)d_in[0];
  const float* k    = (const float*)d_in[1];
  const float* v    = (const float*)d_in[2];
  const float* rel  = (const float*)d_in[3];
  const int*   mask = (const int*)d_in[4];
  const float* Wq   = (const float*)d_in[5];
  const float* bq   = (const float*)d_in[6];
  const float* Wk   = (const float*)d_in[7];
  const float* bk   = (const float*)d_in[8];
  const float* Wv   = (const float*)d_in[9];
  const float* bv   = (const float*)d_in[10];
  const float* Wo   = (const float*)d_in[11];
  const float* bo   = (const float*)d_in[12];
  float* out = (float*)d_out;

  char* ws = (char*)d_ws;
  const size_t SZ_BHLD = (size_t)8 * 16 * 512 * 64 * 4;   // 16.78 MB each
  float* qh = (float*)(ws);
  float* kh = (float*)(ws + SZ_BHLD);
  float* vh = (float*)(ws + 2 * SZ_BHLD);
  unsigned short* X = (unsigned short*)(ws + 3 * SZ_BHLD);            // 25.17 MB
  unsigned short* Y = (unsigned short*)(ws + 3 * SZ_BHLD + 25165824); // 6.29 MB
  unsigned short* qbf = X;
  unsigned short* kbf = X + 4194304;
  unsigned short* vbf = X + 8388608;
  unsigned short* Wqb = Y;
  unsigned short* Wkb = Y + 1048576;
  unsigned short* Wvb = Y + 2097152;

  to_bf16<<<1024, 256, 0, stream>>>(q, qbf, 1048576);
  to_bf16<<<1024, 256, 0, stream>>>(k, kbf, 1048576);
  to_bf16<<<1024, 256, 0, stream>>>(v, vbf, 1048576);
  to_bf16<<<256, 256, 0, stream>>>(Wq, Wqb, 262144);
  to_bf16<<<256, 256, 0, stream>>>(Wk, Wkb, 262144);
  to_bf16<<<256, 256, 0, stream>>>(Wv, Wvb, 262144);

  gemm_bf16<<<256, 256, 0, stream>>>(qbf, 1024, Wqb, 1024, bq, qh, 1024, 0);
  gemm_bf16<<<256, 256, 0, stream>>>(kbf, 1024, Wkb, 1024, bk, kh, 1024, 0);
  gemm_bf16<<<256, 256, 0, stream>>>(vbf, 1024, Wvb, 1024, bv, vh, 1024, 0);

  split3_bf16<<<1024, 256, 0, stream>>>(Wo, Y, 1048576, 1);

  attn_kernel<<<1024, 256, 0, stream>>>(qh, kh, vh, rel, mask, X);

  gemm_bf16<<<256, 256, 0, stream>>>(X, 3072, Y, 3072, bo, out, 3072, 1);
}

// Round 5
// 462.143 us; speedup vs baseline: 1.8369x; 1.4315x over previous
//
#include <hip/hip_runtime.h>

// ---------------- types ----------------
typedef __attribute__((ext_vector_type(8))) short short8;
typedef __attribute__((ext_vector_type(4))) float f32x4;
typedef __attribute__((ext_vector_type(4))) unsigned short u16x4;
typedef unsigned int u32;
typedef unsigned short ushort_t;

union frag_u { u32 w[4]; short8 s; };

static __device__ __forceinline__ unsigned short f2bf(float x) {
  union { float f; unsigned u; } v; v.f = x;
  unsigned r = v.u + 0x7fffu + ((v.u >> 16) & 1u);   // round-to-nearest-even
  return (unsigned short)(r >> 16);
}
static __device__ __forceinline__ float bf2f(unsigned short h) {
  union { unsigned u; float f; } v; v.u = ((unsigned)h) << 16;
  return v.f;
}
static __device__ __forceinline__ u32 pk_bf16(float a, float b) {
  u32 r;
  asm("v_cvt_pk_bf16_f32 %0, %1, %2" : "=v"(r) : "v"(a), "v"(b));
  return r;
}

// async global->LDS, 16B per lane (linear LDS dest = wave base + lane*16)
static __device__ __forceinline__ void gl_lds16(const void* g, void* s) {
  __builtin_amdgcn_global_load_lds(
      (const __attribute__((address_space(1))) void*)g,
      (__attribute__((address_space(3))) void*)s, 16, 0, 0);
}

// ---------------- fp32 -> bf16 (4 elems/thread) ----------------
__global__ __launch_bounds__(256) void to_bf16(const float* __restrict__ src,
                                               ushort_t* __restrict__ dst, int n4) {
  int i = blockIdx.x * blockDim.x + threadIdx.x;
  int stride = gridDim.x * blockDim.x;
  for (; i < n4; i += stride) {
    float4 x = *(const float4*)&src[i * 4];
    u16x4 o;
    o.x = f2bf(x.x); o.y = f2bf(x.y); o.z = f2bf(x.z); o.w = f2bf(x.w);
    *(u16x4*)&dst[i * 4] = o;
  }
}

// fp32 [rows][1024] -> bf16 [rows][3072], bmode 1: [hi | hi | lo] (B side)
__global__ __launch_bounds__(256) void split3_bf16(const float* __restrict__ src,
                                                   ushort_t* __restrict__ dst, int n) {
  int i = blockIdx.x * blockDim.x + threadIdx.x;
  int stride = gridDim.x * blockDim.x;
  for (; i < n; i += stride) {
    int r = i >> 10, c = i & 1023;
    float x = src[i];
    unsigned short hi = f2bf(x);
    unsigned short lo = f2bf(x - bf2f(hi));
    ushort_t* row = dst + (size_t)r * 3072;
    row[c] = hi; row[1024 + c] = hi; row[2048 + c] = lo;
  }
}

// ---------------- bf16 MFMA GEMM (double-buffered, global_load_lds) ----------------
// C[m][n] = sum_k A[m][k] * Bw[n][k] + bias[n]
// mode 0: fp32 permuted qh [b][h][l][d]
// mode 1: fp32 plain [m][1024+n]
// mode 2: bf16 khb [b][h][r][d]
// mode 3: bf16 vT  [b][h][d][r]  (packed ushort4 along r)
__global__ __launch_bounds__(256) void gemm_bf16(const ushort_t* __restrict__ A, int lda,
                                                 const ushort_t* __restrict__ Bw, int ldb,
                                                 const float* __restrict__ bias,
                                                 float* __restrict__ Cout, int K, int mode) {
  __shared__ ushort_t As[2][128 * 32];
  __shared__ ushort_t Bs[2][128 * 32];
  const int t = threadIdx.x;
  const int lane = t & 63;
  const int w = t >> 6;
  const int wr = w >> 1, wc = w & 1;
  const int mt = blockIdx.x >> 3, nt = blockIdx.x & 7;
  const int m0 = mt * 128, n0 = nt * 128;
  const int r16 = lane & 15, kb = lane >> 4;

  f32x4 acc[4][4];
#pragma unroll
  for (int mi = 0; mi < 4; ++mi)
#pragma unroll
    for (int ni = 0; ni < 4; ++ni) acc[mi][ni] = (f32x4){0.f, 0.f, 0.f, 0.f};

  auto STAGE = [&](int buf, int k0) {
#pragma unroll
    for (int i = 0; i < 2; ++i) {
      int c = i * 256 + t;
      int row = c >> 2, kc = (c & 3) * 8;
      gl_lds16(&A[(size_t)(m0 + row) * lda + k0 + kc], &As[buf][c * 8]);
      gl_lds16(&Bw[(size_t)(n0 + row) * ldb + k0 + kc], &Bs[buf][c * 8]);
    }
  };

  const int NT = K / 32;
  STAGE(0, 0);
  __syncthreads();
  int cur = 0;
  for (int kt = 0; kt < NT; ++kt) {
    if (kt + 1 < NT) STAGE(cur ^ 1, (kt + 1) * 32);
    short8 af[4], bf[4];
#pragma unroll
    for (int mi = 0; mi < 4; ++mi)
      af[mi] = *(const short8*)&As[cur][(wr * 64 + mi * 16 + r16) * 32 + kb * 8];
#pragma unroll
    for (int ni = 0; ni < 4; ++ni)
      bf[ni] = *(const short8*)&Bs[cur][(wc * 64 + ni * 16 + r16) * 32 + kb * 8];
#pragma unroll
    for (int mi = 0; mi < 4; ++mi)
#pragma unroll
      for (int ni = 0; ni < 4; ++ni)
        acc[mi][ni] = __builtin_amdgcn_mfma_f32_16x16x32_bf16(af[mi], bf[ni], acc[mi][ni], 0, 0, 0);
    __syncthreads();
    cur ^= 1;
  }

  const int rowD = (lane >> 4) * 4;
#pragma unroll
  for (int mi = 0; mi < 4; ++mi) {
#pragma unroll
    for (int ni = 0; ni < 4; ++ni) {
      int n = n0 + wc * 64 + ni * 16 + (lane & 15);
      float bv = bias[n];
      int mbase = m0 + wr * 64 + mi * 16 + rowD;
      float vals[4];
#pragma unroll
      for (int j = 0; j < 4; ++j) vals[j] = acc[mi][ni][j] + bv;
      if (mode == 0) {
#pragma unroll
        for (int j = 0; j < 4; ++j) {
          int m = mbase + j;
          int b = m >> 9, l = m & 511, hh = n >> 6, d = n & 63;
          Cout[(((size_t)(b * 16 + hh)) * 512 + l) * 64 + d] = vals[j];
        }
      } else if (mode == 1) {
#pragma unroll
        for (int j = 0; j < 4; ++j)
          Cout[(size_t)(mbase + j) * 1024 + n] = vals[j];
      } else if (mode == 2) {
        ushort_t* co = (ushort_t*)Cout;
#pragma unroll
        for (int j = 0; j < 4; ++j) {
          int m = mbase + j;
          int b = m >> 9, r = m & 511, hh = n >> 6, d = n & 63;
          co[(((size_t)(b * 16 + hh)) * 512 + r) * 64 + d] = f2bf(vals[j]);
        }
      } else {
        ushort_t* co = (ushort_t*)Cout;
        int b = mbase >> 9, r = mbase & 511, hh = n >> 6, d = n & 63;
        u16x4 pkv;
        pkv.x = f2bf(vals[0]); pkv.y = f2bf(vals[1]);
        pkv.z = f2bf(vals[2]); pkv.w = f2bf(vals[3]);
        *(u16x4*)&co[(((size_t)(b * 16 + hh)) * 64 + d) * 512 + r] = pkv;
      }
    }
  }
}

// ---------------- fused attention, full MFMA ----------------
// grid: 512 wgs (16 h x 32 l-tiles, XCD-pinned). wg = 256 thr = 4 waves.
// Wave w: owns batches {2w, 2w+1} (QK, softmax, PV) and rel rows l = 4w..4w+3.
// All score fragments in C[r-row][col] orientation (swapped mfma(K,Q)).
__global__ __launch_bounds__(256, 2) void attn_mfma(
    const float* __restrict__ qh, const ushort_t* __restrict__ khb,
    const ushort_t* __restrict__ vT, const float* __restrict__ rel,
    const int* __restrict__ mask, ushort_t* __restrict__ Abig) {
  __shared__ ushort_t qs[8][16][64];          // bf16 q [b][l][d]
  __shared__ float sp2[2][8][16][20];         // rel scores exchange [buf][b][l][r(+pad)]
  const int t = threadIdx.x;
  const int w = t >> 6, lane = t & 63, lh = lane & 15, lg = lane >> 4;
  const int bid = blockIdx.x;
  const int slot = bid & 7, grp = bid >> 3;
  const int h = slot * 2 + (grp & 1);         // heads {2s,2s+1} pinned to XCD s
  const int l0 = (grp >> 1) * 16;
  const int b0 = w * 2;

  // ---- stage q (fp32 -> bf16) into qs ----
  {
    int idx = t * 32;
    int b = idx >> 10, l = (idx >> 6) & 15, d0 = idx & 63;   // d0 in {0,32}
    const float* src = &qh[(((size_t)(b * 16 + h)) * 512 + l0 + l) * 64 + d0];
    ushort_t* dst = &qs[b][l][d0];
#pragma unroll
    for (int j = 0; j < 8; ++j) {
      f32x4 xv = *(const f32x4*)&src[j * 4];
      u32 w0 = pk_bf16(xv[0], xv[1]), w1 = pk_bf16(xv[2], xv[3]);
      *(u32*)&dst[j * 4] = w0;
      *(u32*)&dst[j * 4 + 2] = w1;
    }
  }

  // rel register prefetch: R[li*4 + kb*2 + q] = rel[l0+4w+li][r0+lh][h*64+kb*32+lg*8 (+4q)]
  f32x4 R[16];
  auto LOAD_REL = [&](int r0_) {
#pragma unroll
    for (int li = 0; li < 4; ++li) {
      const float* rp = &rel[((size_t)(l0 + w * 4 + li) * 512 + r0_ + lh) * 1024 + h * 64 + lg * 8];
#pragma unroll
      for (int kb = 0; kb < 2; ++kb) {
        R[li * 4 + kb * 2 + 0] = *(const f32x4*)&rp[kb * 32];
        R[li * 4 + kb * 2 + 1] = *(const f32x4*)&rp[kb * 32 + 4];
      }
    }
  };
  LOAD_REL(0);

  f32x4 O[2][4];                              // [b-hat][d-tile], rows d=4lg+j, col l=lh
#pragma unroll
  for (int i = 0; i < 2; ++i)
#pragma unroll
    for (int j = 0; j < 4; ++j) O[i][j] = (f32x4){0.f, 0.f, 0.f, 0.f};
  float m_run[2] = {-1e30f, -1e30f}, s_run[2] = {0.f, 0.f};

  __syncthreads();

  for (int it = 0; it < 32; ++it) {
    const int r0 = it * 16;
    const int cur = it & 1;

    // issue K / V fragment loads early (L2-resident, latency hidden under rel phase)
    short8 kf[2][2], vf[2][4];
#pragma unroll
    for (int bh = 0; bh < 2; ++bh) {
#pragma unroll
      for (int kb = 0; kb < 2; ++kb)
        kf[bh][kb] = *(const short8*)&khb[(((size_t)((b0 + bh) * 16 + h)) * 512 + r0 + lh) * 64 + kb * 32 + lg * 8];
#pragma unroll
      for (int dt = 0; dt < 4; ++dt)
        vf[bh][dt] = *(const short8*)&vT[(((size_t)((b0 + bh) * 16 + h)) * 64 + dt * 16 + lh) * 512 + r0 + lg * 8];
    }
    int4 mk = *(const int4*)&mask[(size_t)(l0 + lh) * 512 + r0 + lg * 4];

    // ---- rel-term MFMA: A = rel rows (m=r), B = q cols (n=b) -> sp2[b][l][r] ----
#pragma unroll
    for (int li = 0; li < 4; ++li) {
      frag_u a0, a1;
      f32x4 v00 = R[li * 4 + 0], v01 = R[li * 4 + 1];
      f32x4 v10 = R[li * 4 + 2], v11 = R[li * 4 + 3];
      a0.w[0] = pk_bf16(v00[0], v00[1]); a0.w[1] = pk_bf16(v00[2], v00[3]);
      a0.w[2] = pk_bf16(v01[0], v01[1]); a0.w[3] = pk_bf16(v01[2], v01[3]);
      a1.w[0] = pk_bf16(v10[0], v10[1]); a1.w[1] = pk_bf16(v10[2], v10[3]);
      a1.w[2] = pk_bf16(v11[0], v11[1]); a1.w[3] = pk_bf16(v11[2], v11[3]);
      short8 q0 = *(const short8*)&qs[lh & 7][w * 4 + li][lg * 8];
      short8 q1 = *(const short8*)&qs[lh & 7][w * 4 + li][32 + lg * 8];
      f32x4 acc = (f32x4){0.f, 0.f, 0.f, 0.f};
      acc = __builtin_amdgcn_mfma_f32_16x16x32_bf16(a0.s, q0, acc, 0, 0, 0);
      acc = __builtin_amdgcn_mfma_f32_16x16x32_bf16(a1.s, q1, acc, 0, 0, 0);
      if (lh < 8) *(f32x4*)&sp2[cur][lh][w * 4 + li][lg * 4] = acc;
    }
    // prefetch next rel tile (R dead after cvt above)
    if (it < 31) LOAD_REL(r0 + 16);
    __syncthreads();

    // ---- per owned batch: QK + softmax + PV ----
#pragma unroll
    for (int bh = 0; bh < 2; ++bh) {
      short8 qb0 = *(const short8*)&qs[b0 + bh][lh][lg * 8];
      short8 qb1 = *(const short8*)&qs[b0 + bh][lh][32 + lg * 8];
      f32x4 s1 = (f32x4){0.f, 0.f, 0.f, 0.f};
      s1 = __builtin_amdgcn_mfma_f32_16x16x32_bf16(kf[bh][0], qb0, s1, 0, 0, 0);
      s1 = __builtin_amdgcn_mfma_f32_16x16x32_bf16(kf[bh][1], qb1, s1, 0, 0, 0);
      f32x4 s2 = *(const f32x4*)&sp2[cur][b0 + bh][lh][lg * 4];
      f32x4 S;
      S[0] = (mk.x == 0) ? -1e9f : (s1[0] * 0.125f + s2[0]);
      S[1] = (mk.y == 0) ? -1e9f : (s1[1] * 0.125f + s2[1]);
      S[2] = (mk.z == 0) ? -1e9f : (s1[2] * 0.125f + s2[2]);
      S[3] = (mk.w == 0) ? -1e9f : (s1[3] * 0.125f + s2[3]);
      // row stats over r (4 regs + lanes lh, lh+16, lh+32, lh+48)
      float mt = fmaxf(fmaxf(S[0], S[1]), fmaxf(S[2], S[3]));
      mt = fmaxf(mt, __shfl_xor(mt, 16));
      mt = fmaxf(mt, __shfl_xor(mt, 32));
      float mn = fmaxf(m_run[bh], mt);
      float fsc = __expf(m_run[bh] - mn);
      f32x4 P;
      P[0] = __expf(S[0] - mn); P[1] = __expf(S[1] - mn);
      P[2] = __expf(S[2] - mn); P[3] = __expf(S[3] - mn);
      float ps = P[0] + P[1] + P[2] + P[3];
      ps += __shfl_xor(ps, 16);
      ps += __shfl_xor(ps, 32);
      s_run[bh] = s_run[bh] * fsc + ps;
      m_run[bh] = mn;
#pragma unroll
      for (int dt = 0; dt < 4; ++dt) O[bh][dt] *= fsc;
      // P (C-layout) -> B-fragment (k=r): cvt_pk + 4 shfl; upper K half zero
      u32 pk0 = pk_bf16(P[0], P[1]), pk1 = pk_bf16(P[2], P[3]);
      int s0l = (lh + 32 * lg) & 63;
      u32 w0 = (u32)__shfl((int)pk0, s0l), w1 = (u32)__shfl((int)pk1, s0l);
      u32 w2 = (u32)__shfl((int)pk0, s0l + 16), w3 = (u32)__shfl((int)pk1, s0l + 16);
      bool vld = (lg < 2);
      frag_u pb;
      pb.w[0] = vld ? w0 : 0u; pb.w[1] = vld ? w1 : 0u;
      pb.w[2] = vld ? w2 : 0u; pb.w[3] = vld ? w3 : 0u;
#pragma unroll
      for (int dt = 0; dt < 4; ++dt)
        O[bh][dt] = __builtin_amdgcn_mfma_f32_16x16x32_bf16(vf[bh][dt], pb.s, O[bh][dt], 0, 0, 0);
    }
  }

  // ---- epilogue: O /= s; hi/lo/hi bf16 split into Abig [b*512+l][3072] ----
#pragma unroll
  for (int bh = 0; bh < 2; ++bh) {
    float inv = 1.0f / s_run[bh];
    ushort_t* rowp = &Abig[(size_t)((b0 + bh) * 512 + l0 + lh) * 3072];
#pragma unroll
    for (int dt = 0; dt < 4; ++dt) {
      int c = h * 64 + dt * 16 + lg * 4;
      f32x4 o = O[bh][dt];
      float x0 = o[0] * inv, x1 = o[1] * inv, x2 = o[2] * inv, x3 = o[3] * inv;
      u16x4 hi, lo;
      hi.x = f2bf(x0); lo.x = f2bf(x0 - bf2f(hi.x));
      hi.y = f2bf(x1); lo.y = f2bf(x1 - bf2f(hi.y));
      hi.z = f2bf(x2); lo.z = f2bf(x2 - bf2f(hi.z));
      hi.w = f2bf(x3); lo.w = f2bf(x3 - bf2f(hi.w));
      *(u16x4*)&rowp[c] = hi;
      *(u16x4*)&rowp[1024 + c] = lo;
      *(u16x4*)&rowp[2048 + c] = hi;
    }
  }
}

// ---------------- launcher ----------------
extern "C" void kernel_launch(void* const* d_in, const int* in_sizes, int n_in,
                              void* d_out, int out_size, void* d_ws, size_t ws_size,
                              hipStream_t stream) {
  const float* q    = (const float*)d_in[0];
  const float* k    = (const float*)d_in[1];
  const float* v    = (const float*)d_in[2];
  const float* rel  = (const float*)d_in[3];
  const int*   mask = (const int*)d_in[4];
  const float* Wq   = (const float*)d_in[5];
  const float* bq   = (const float*)d_in[6];
  const float* Wk   = (const float*)d_in[7];
  const float* bk   = (const float*)d_in[8];
  const float* Wv   = (const float*)d_in[9];
  const float* bv   = (const float*)d_in[10];
  const float* Wo   = (const float*)d_in[11];
  const float* bo   = (const float*)d_in[12];
  float* out = (float*)d_out;

  char* ws = (char*)d_ws;
  float*    qh  = (float*)(ws);                          // 16.78 MB fp32 [b][h][l][d]
  ushort_t* khb = (ushort_t*)(ws + 16777216);            // 8.39 MB bf16 [b][h][r][d]
  ushort_t* vT  = (ushort_t*)(ws + 16777216 + 8388608);  // 8.39 MB bf16 [b][h][d][r]
  ushort_t* X   = (ushort_t*)(ws + 33554432);            // 25.17 MB: qbf/kbf/vbf then Abig
  ushort_t* Y   = (ushort_t*)(ws + 58720256);            // 6.29 MB: W*bf then Wo split
  ushort_t* qbf = X;
  ushort_t* kbf = X + 4194304;
  ushort_t* vbf = X + 8388608;
  ushort_t* Wqb = Y;
  ushort_t* Wkb = Y + 1048576;
  ushort_t* Wvb = Y + 2097152;

  to_bf16<<<1024, 256, 0, stream>>>(q, qbf, 1048576);
  to_bf16<<<1024, 256, 0, stream>>>(k, kbf, 1048576);
  to_bf16<<<1024, 256, 0, stream>>>(v, vbf, 1048576);
  to_bf16<<<256, 256, 0, stream>>>(Wq, Wqb, 262144);
  to_bf16<<<256, 256, 0, stream>>>(Wk, Wkb, 262144);
  to_bf16<<<256, 256, 0, stream>>>(Wv, Wvb, 262144);

  gemm_bf16<<<256, 256, 0, stream>>>(qbf, 1024, Wqb, 1024, bq, qh, 1024, 0);
  gemm_bf16<<<256, 256, 0, stream>>>(kbf, 1024, Wkb, 1024, bk, (float*)khb, 1024, 2);
  gemm_bf16<<<256, 256, 0, stream>>>(vbf, 1024, Wvb, 1024, bv, (float*)vT, 1024, 3);

  split3_bf16<<<1024, 256, 0, stream>>>(Wo, Y, 1048576);

  attn_mfma<<<512, 256, 0, stream>>>(qh, khb, vT, rel, mask, X);

  gemm_bf16<<<256, 256, 0, stream>>>(X, 3072, Y, 3072, bo, out, 3072, 1);
}

// Round 6
// 438.827 us; speedup vs baseline: 1.9345x; 1.0531x over previous
//
#include <hip/hip_runtime.h>

// ---------------- types ----------------
typedef __attribute__((ext_vector_type(8))) short short8;
typedef __attribute__((ext_vector_type(4))) float f32x4;
typedef __attribute__((ext_vector_type(4))) unsigned short u16x4;
typedef unsigned int u32;
typedef unsigned short ushort_t;

union frag_u { u32 w[4]; short8 s; };

static __device__ __forceinline__ unsigned short f2bf(float x) {
  union { float f; unsigned u; } v; v.f = x;
  unsigned r = v.u + 0x7fffu + ((v.u >> 16) & 1u);   // round-to-nearest-even
  return (unsigned short)(r >> 16);
}
static __device__ __forceinline__ float bf2f(unsigned short h) {
  union { unsigned u; float f; } v; v.u = ((unsigned)h) << 16;
  return v.f;
}
static __device__ __forceinline__ u32 pk_bf16(float a, float b) {
  u32 r;
  asm("v_cvt_pk_bf16_f32 %0, %1, %2" : "=v"(r) : "v"(a), "v"(b));
  return r;
}

// async global->LDS, 16B per lane (linear LDS dest = wave base + lane*16)
static __device__ __forceinline__ void gl_lds16(const void* g, void* s) {
  __builtin_amdgcn_global_load_lds(
      (const __attribute__((address_space(1))) void*)g,
      (__attribute__((address_space(3))) void*)s, 16, 0, 0);
}

// ---------------- fp32 -> bf16 (4 elems/thread) ----------------
__global__ __launch_bounds__(256) void to_bf16(const float* __restrict__ src,
                                               ushort_t* __restrict__ dst, int n4) {
  int i = blockIdx.x * blockDim.x + threadIdx.x;
  int stride = gridDim.x * blockDim.x;
  for (; i < n4; i += stride) {
    float4 x = *(const float4*)&src[i * 4];
    u16x4 o;
    o.x = f2bf(x.x); o.y = f2bf(x.y); o.z = f2bf(x.z); o.w = f2bf(x.w);
    *(u16x4*)&dst[i * 4] = o;
  }
}

// fp32 [rows][1024] -> bf16 [rows][3072]: [hi | hi | lo] (B side)
__global__ __launch_bounds__(256) void split3_bf16(const float* __restrict__ src,
                                                   ushort_t* __restrict__ dst, int n) {
  int i = blockIdx.x * blockDim.x + threadIdx.x;
  int stride = gridDim.x * blockDim.x;
  for (; i < n; i += stride) {
    int r = i >> 10, c = i & 1023;
    float x = src[i];
    unsigned short hi = f2bf(x);
    unsigned short lo = f2bf(x - bf2f(hi));
    ushort_t* row = dst + (size_t)r * 3072;
    row[c] = hi; row[1024 + c] = hi; row[2048 + c] = lo;
  }
}

// ---------------- merged QKV projection GEMM ----------------
// 768 wgs: mt = bid/24 (M=4096, 32 tiles), ntg = bid%24: which = ntg>>3, nt = ntg&7
// which 0: qh fp32 [b][h][l][d];  1: khb bf16 [b][h][r][d];  2: vT bf16 [b][h][d][r]
__global__ __launch_bounds__(256) void gemm_qkv(
    const ushort_t* __restrict__ qbf, const ushort_t* __restrict__ kbf,
    const ushort_t* __restrict__ vbf, const ushort_t* __restrict__ Wqb,
    const ushort_t* __restrict__ Wkb, const ushort_t* __restrict__ Wvb,
    const float* __restrict__ bq, const float* __restrict__ bk,
    const float* __restrict__ bv, float* __restrict__ qh,
    ushort_t* __restrict__ khb, ushort_t* __restrict__ vT) {
  __shared__ ushort_t As[2][128 * 32];
  __shared__ ushort_t Bs[2][128 * 32];
  const int t = threadIdx.x;
  const int lane = t & 63;
  const int w = t >> 6;
  const int wr = w >> 1, wc = w & 1;
  const int bid = blockIdx.x;
  const int mt = bid / 24, ntg = bid % 24;
  const int which = ntg >> 3, nt = ntg & 7;
  const ushort_t* A  = which == 0 ? qbf : which == 1 ? kbf : vbf;
  const ushort_t* Bw = which == 0 ? Wqb : which == 1 ? Wkb : Wvb;
  const float* bias  = which == 0 ? bq  : which == 1 ? bk  : bv;
  const int m0 = mt * 128, n0 = nt * 128;
  const int r16 = lane & 15, kb = lane >> 4;

  f32x4 acc[4][4];
#pragma unroll
  for (int mi = 0; mi < 4; ++mi)
#pragma unroll
    for (int ni = 0; ni < 4; ++ni) acc[mi][ni] = (f32x4){0.f, 0.f, 0.f, 0.f};

  auto STAGE = [&](int buf, int k0) {
#pragma unroll
    for (int i = 0; i < 2; ++i) {
      int c = i * 256 + t;
      int row = c >> 2, kc = (c & 3) * 8;
      gl_lds16(&A[(size_t)(m0 + row) * 1024 + k0 + kc], &As[buf][c * 8]);
      gl_lds16(&Bw[(size_t)(n0 + row) * 1024 + k0 + kc], &Bs[buf][c * 8]);
    }
  };

  STAGE(0, 0);
  __syncthreads();
  int cur = 0;
  for (int kt = 0; kt < 32; ++kt) {
    if (kt + 1 < 32) STAGE(cur ^ 1, (kt + 1) * 32);
    short8 af[4], bf[4];
#pragma unroll
    for (int mi = 0; mi < 4; ++mi)
      af[mi] = *(const short8*)&As[cur][(wr * 64 + mi * 16 + r16) * 32 + kb * 8];
#pragma unroll
    for (int ni = 0; ni < 4; ++ni)
      bf[ni] = *(const short8*)&Bs[cur][(wc * 64 + ni * 16 + r16) * 32 + kb * 8];
#pragma unroll
    for (int mi = 0; mi < 4; ++mi)
#pragma unroll
      for (int ni = 0; ni < 4; ++ni)
        acc[mi][ni] = __builtin_amdgcn_mfma_f32_16x16x32_bf16(af[mi], bf[ni], acc[mi][ni], 0, 0, 0);
    __syncthreads();
    cur ^= 1;
  }

  const int rowD = (lane >> 4) * 4;
#pragma unroll
  for (int mi = 0; mi < 4; ++mi) {
#pragma unroll
    for (int ni = 0; ni < 4; ++ni) {
      int n = n0 + wc * 64 + ni * 16 + (lane & 15);
      float bv4 = bias[n];
      int mbase = m0 + wr * 64 + mi * 16 + rowD;
      float vals[4];
#pragma unroll
      for (int j = 0; j < 4; ++j) vals[j] = acc[mi][ni][j] + bv4;
      int hh = n >> 6, d = n & 63;
      if (which == 0) {
#pragma unroll
        for (int j = 0; j < 4; ++j) {
          int m = mbase + j;
          int b = m >> 9, l = m & 511;
          qh[(((size_t)(b * 16 + hh)) * 512 + l) * 64 + d] = vals[j];
        }
      } else if (which == 1) {
#pragma unroll
        for (int j = 0; j < 4; ++j) {
          int m = mbase + j;
          int b = m >> 9, r = m & 511;
          khb[(((size_t)(b * 16 + hh)) * 512 + r) * 64 + d] = f2bf(vals[j]);
        }
      } else {
        int b = mbase >> 9, r = mbase & 511;
        u16x4 pkv;
        pkv.x = f2bf(vals[0]); pkv.y = f2bf(vals[1]);
        pkv.z = f2bf(vals[2]); pkv.w = f2bf(vals[3]);
        *(u16x4*)&vT[(((size_t)(b * 16 + hh)) * 64 + d) * 512 + r] = pkv;
      }
    }
  }
}

// ---------------- final O-projection GEMM (K=3072 split) ----------------
__global__ __launch_bounds__(256) void gemm_out(const ushort_t* __restrict__ A,
                                                const ushort_t* __restrict__ Bw,
                                                const float* __restrict__ bias,
                                                float* __restrict__ Cout) {
  __shared__ ushort_t As[2][128 * 32];
  __shared__ ushort_t Bs[2][128 * 32];
  const int t = threadIdx.x;
  const int lane = t & 63;
  const int w = t >> 6;
  const int wr = w >> 1, wc = w & 1;
  const int mt = blockIdx.x >> 3, nt = blockIdx.x & 7;
  const int m0 = mt * 128, n0 = nt * 128;
  const int r16 = lane & 15, kb = lane >> 4;

  f32x4 acc[4][4];
#pragma unroll
  for (int mi = 0; mi < 4; ++mi)
#pragma unroll
    for (int ni = 0; ni < 4; ++ni) acc[mi][ni] = (f32x4){0.f, 0.f, 0.f, 0.f};

  auto STAGE = [&](int buf, int k0) {
#pragma unroll
    for (int i = 0; i < 2; ++i) {
      int c = i * 256 + t;
      int row = c >> 2, kc = (c & 3) * 8;
      gl_lds16(&A[(size_t)(m0 + row) * 3072 + k0 + kc], &As[buf][c * 8]);
      gl_lds16(&Bw[(size_t)(n0 + row) * 3072 + k0 + kc], &Bs[buf][c * 8]);
    }
  };

  STAGE(0, 0);
  __syncthreads();
  int cur = 0;
  for (int kt = 0; kt < 96; ++kt) {
    if (kt + 1 < 96) STAGE(cur ^ 1, (kt + 1) * 32);
    short8 af[4], bf[4];
#pragma unroll
    for (int mi = 0; mi < 4; ++mi)
      af[mi] = *(const short8*)&As[cur][(wr * 64 + mi * 16 + r16) * 32 + kb * 8];
#pragma unroll
    for (int ni = 0; ni < 4; ++ni)
      bf[ni] = *(const short8*)&Bs[cur][(wc * 64 + ni * 16 + r16) * 32 + kb * 8];
#pragma unroll
    for (int mi = 0; mi < 4; ++mi)
#pragma unroll
      for (int ni = 0; ni < 4; ++ni)
        acc[mi][ni] = __builtin_amdgcn_mfma_f32_16x16x32_bf16(af[mi], bf[ni], acc[mi][ni], 0, 0, 0);
    __syncthreads();
    cur ^= 1;
  }

  const int rowD = (lane >> 4) * 4;
#pragma unroll
  for (int mi = 0; mi < 4; ++mi) {
#pragma unroll
    for (int ni = 0; ni < 4; ++ni) {
      int n = n0 + wc * 64 + ni * 16 + (lane & 15);
      float bv = bias[n];
      int mbase = m0 + wr * 64 + mi * 16 + rowD;
#pragma unroll
      for (int j = 0; j < 4; ++j)
        Cout[(size_t)(mbase + j) * 1024 + n] = acc[mi][ni][j] + bv;
    }
  }
}

// ---------------- fused attention, full MFMA, XOR-swizzled LDS ----------------
// grid: 512 wgs (16 h x 32 l-tiles, XCD-pinned). wg = 256 thr = 4 waves.
// Wave w: owns batches {2w, 2w+1} (QK, softmax, PV) and rel rows l = 4w..4w+3.
// qs 16B-block swizzle: block j of row (b,l) stored at j ^ (l&7) ^ b.
__global__ __launch_bounds__(256, 2) void attn_mfma(
    const float* __restrict__ qh, const ushort_t* __restrict__ khb,
    const ushort_t* __restrict__ vT, const float* __restrict__ rel,
    const int* __restrict__ mask, ushort_t* __restrict__ Abig) {
  __shared__ ushort_t qs[8][16][64];          // bf16 q [b][l][8 blocks of 8, swizzled]
  __shared__ float sp2[2][8][17][20];         // rel scores [buf][b][l(+1 pad)][r(+pad)]
  const int t = threadIdx.x;
  const int w = t >> 6, lane = t & 63, lh = lane & 15, lg = lane >> 4;
  const int bid = blockIdx.x;
  const int slot = bid & 7, grp = bid >> 3;
  const int h = slot * 2 + (grp & 1);         // heads {2s,2s+1} pinned to XCD s
  const int l0 = (grp >> 1) * 16;
  const int b0 = w * 2;

  // ---- stage q (fp32 -> bf16) into swizzled qs ----
  {
    int idx = t * 32;
    int b = idx >> 10, l = (idx >> 6) & 15, d0 = idx & 63;   // d0 in {0,32}
    const float* src = &qh[(((size_t)(b * 16 + h)) * 512 + l0 + l) * 64 + d0];
    int xr = (l & 7) ^ b;
#pragma unroll
    for (int jj = 0; jj < 4; ++jj) {
      f32x4 x0 = *(const f32x4*)&src[jj * 8];
      f32x4 x1 = *(const f32x4*)&src[jj * 8 + 4];
      frag_u fu;
      fu.w[0] = pk_bf16(x0[0], x0[1]); fu.w[1] = pk_bf16(x0[2], x0[3]);
      fu.w[2] = pk_bf16(x1[0], x1[1]); fu.w[3] = pk_bf16(x1[2], x1[3]);
      int pos = ((d0 >> 3) + jj) ^ xr;
      *(short8*)&qs[b][l][pos * 8] = fu.s;
    }
  }

  // rel register prefetch: R[li*4 + kb*2 + q] = rel[l0+4w+li][r0+lh][h*64+kb*32+lg*8 (+4q)]
  f32x4 R[16];
  auto LOAD_REL = [&](int r0_) {
#pragma unroll
    for (int li = 0; li < 4; ++li) {
      const float* rp = &rel[((size_t)(l0 + w * 4 + li) * 512 + r0_ + lh) * 1024 + h * 64 + lg * 8];
#pragma unroll
      for (int kb = 0; kb < 2; ++kb) {
        R[li * 4 + kb * 2 + 0] = *(const f32x4*)&rp[kb * 32];
        R[li * 4 + kb * 2 + 1] = *(const f32x4*)&rp[kb * 32 + 4];
      }
    }
  };
  LOAD_REL(0);

  f32x4 O[2][4];                              // [b-hat][d-tile], rows d=4lg+j, col l=lh
#pragma unroll
  for (int i = 0; i < 2; ++i)
#pragma unroll
    for (int j = 0; j < 4; ++j) O[i][j] = (f32x4){0.f, 0.f, 0.f, 0.f};
  float m_run[2] = {-1e30f, -1e30f}, s_run[2] = {0.f, 0.f};

  __syncthreads();

  for (int it = 0; it < 32; ++it) {
    const int r0 = it * 16;
    const int cur = it & 1;

    // issue K / V fragment loads early (L2-resident, latency hidden under rel phase)
    short8 kf[2][2], vf[2][4];
#pragma unroll
    for (int bh = 0; bh < 2; ++bh) {
#pragma unroll
      for (int kb = 0; kb < 2; ++kb)
        kf[bh][kb] = *(const short8*)&khb[(((size_t)((b0 + bh) * 16 + h)) * 512 + r0 + lh) * 64 + kb * 32 + lg * 8];
#pragma unroll
      for (int dt = 0; dt < 4; ++dt)
        vf[bh][dt] = *(const short8*)&vT[(((size_t)((b0 + bh) * 16 + h)) * 64 + dt * 16 + lh) * 512 + r0 + lg * 8];
    }
    int4 mk = *(const int4*)&mask[(size_t)(l0 + lh) * 512 + r0 + lg * 4];

    // ---- rel-term MFMA: A = rel rows (m=r), B = q cols (n=b) -> sp2[b][l][r] ----
#pragma unroll
    for (int li = 0; li < 4; ++li) {
      frag_u a0, a1;
      f32x4 v00 = R[li * 4 + 0], v01 = R[li * 4 + 1];
      f32x4 v10 = R[li * 4 + 2], v11 = R[li * 4 + 3];
      a0.w[0] = pk_bf16(v00[0], v00[1]); a0.w[1] = pk_bf16(v00[2], v00[3]);
      a0.w[2] = pk_bf16(v01[0], v01[1]); a0.w[3] = pk_bf16(v01[2], v01[3]);
      a1.w[0] = pk_bf16(v10[0], v10[1]); a1.w[1] = pk_bf16(v10[2], v10[3]);
      a1.w[2] = pk_bf16(v11[0], v11[1]); a1.w[3] = pk_bf16(v11[2], v11[3]);
      int l = w * 4 + li;
      int xr2 = (l & 7) ^ (lh & 7);
      short8 q0 = *(const short8*)&qs[lh & 7][l][(lg ^ xr2) * 8];
      short8 q1 = *(const short8*)&qs[lh & 7][l][((4 + lg) ^ xr2) * 8];
      f32x4 acc = (f32x4){0.f, 0.f, 0.f, 0.f};
      acc = __builtin_amdgcn_mfma_f32_16x16x32_bf16(a0.s, q0, acc, 0, 0, 0);
      acc = __builtin_amdgcn_mfma_f32_16x16x32_bf16(a1.s, q1, acc, 0, 0, 0);
      if (lh < 8) *(f32x4*)&sp2[cur][lh][l][lg * 4] = acc;
    }
    // prefetch next rel tile (R dead after cvt above)
    if (it < 31) LOAD_REL(r0 + 16);
    __syncthreads();

    // ---- per owned batch: QK + softmax + PV ----
    __builtin_amdgcn_s_setprio(1);
#pragma unroll
    for (int bh = 0; bh < 2; ++bh) {
      int xqk = (lh & 7) ^ (b0 + bh);
      short8 qb0 = *(const short8*)&qs[b0 + bh][lh][(lg ^ xqk) * 8];
      short8 qb1 = *(const short8*)&qs[b0 + bh][lh][((4 + lg) ^ xqk) * 8];
      f32x4 s1 = (f32x4){0.f, 0.f, 0.f, 0.f};
      s1 = __builtin_amdgcn_mfma_f32_16x16x32_bf16(kf[bh][0], qb0, s1, 0, 0, 0);
      s1 = __builtin_amdgcn_mfma_f32_16x16x32_bf16(kf[bh][1], qb1, s1, 0, 0, 0);
      f32x4 s2 = *(const f32x4*)&sp2[cur][b0 + bh][lh][lg * 4];
      f32x4 S;
      S[0] = (mk.x == 0) ? -1e9f : (s1[0] * 0.125f + s2[0]);
      S[1] = (mk.y == 0) ? -1e9f : (s1[1] * 0.125f + s2[1]);
      S[2] = (mk.z == 0) ? -1e9f : (s1[2] * 0.125f + s2[2]);
      S[3] = (mk.w == 0) ? -1e9f : (s1[3] * 0.125f + s2[3]);
      // row stats over r (4 regs + lanes lh, lh+16, lh+32, lh+48)
      float mt = fmaxf(fmaxf(S[0], S[1]), fmaxf(S[2], S[3]));
      mt = fmaxf(mt, __shfl_xor(mt, 16));
      mt = fmaxf(mt, __shfl_xor(mt, 32));
      float mn = fmaxf(m_run[bh], mt);
      float fsc = __expf(m_run[bh] - mn);
      f32x4 P;
      P[0] = __expf(S[0] - mn); P[1] = __expf(S[1] - mn);
      P[2] = __expf(S[2] - mn); P[3] = __expf(S[3] - mn);
      float ps = P[0] + P[1] + P[2] + P[3];
      ps += __shfl_xor(ps, 16);
      ps += __shfl_xor(ps, 32);
      s_run[bh] = s_run[bh] * fsc + ps;
      m_run[bh] = mn;
#pragma unroll
      for (int dt = 0; dt < 4; ++dt) O[bh][dt] *= fsc;
      // P (C-layout) -> B-fragment (k=r): cvt_pk + 4 shfl; upper K half zero
      u32 pk0 = pk_bf16(P[0], P[1]), pk1 = pk_bf16(P[2], P[3]);
      int s0l = (lh + 32 * lg) & 63;
      u32 w0 = (u32)__shfl((int)pk0, s0l), w1 = (u32)__shfl((int)pk1, s0l);
      u32 w2 = (u32)__shfl((int)pk0, s0l + 16), w3 = (u32)__shfl((int)pk1, s0l + 16);
      bool vld = (lg < 2);
      frag_u pb;
      pb.w[0] = vld ? w0 : 0u; pb.w[1] = vld ? w1 : 0u;
      pb.w[2] = vld ? w2 : 0u; pb.w[3] = vld ? w3 : 0u;
#pragma unroll
      for (int dt = 0; dt < 4; ++dt)
        O[bh][dt] = __builtin_amdgcn_mfma_f32_16x16x32_bf16(vf[bh][dt], pb.s, O[bh][dt], 0, 0, 0);
    }
    __builtin_amdgcn_s_setprio(0);
  }

  // ---- epilogue: O /= s; hi/lo/hi bf16 split into Abig [b*512+l][3072] ----
#pragma unroll
  for (int bh = 0; bh < 2; ++bh) {
    float inv = 1.0f / s_run[bh];
    ushort_t* rowp = &Abig[(size_t)((b0 + bh) * 512 + l0 + lh) * 3072];
#pragma unroll
    for (int dt = 0; dt < 4; ++dt) {
      int c = h * 64 + dt * 16 + lg * 4;
      f32x4 o = O[bh][dt];
      float x0 = o[0] * inv, x1 = o[1] * inv, x2 = o[2] * inv, x3 = o[3] * inv;
      u16x4 hi, lo;
      hi.x = f2bf(x0); lo.x = f2bf(x0 - bf2f(hi.x));
      hi.y = f2bf(x1); lo.y = f2bf(x1 - bf2f(hi.y));
      hi.z = f2bf(x2); lo.z = f2bf(x2 - bf2f(hi.z));
      hi.w = f2bf(x3); lo.w = f2bf(x3 - bf2f(hi.w));
      *(u16x4*)&rowp[c] = hi;
      *(u16x4*)&rowp[1024 + c] = lo;
      *(u16x4*)&rowp[2048 + c] = hi;
    }
  }
}

// ---------------- launcher ----------------
extern "C" void kernel_launch(void* const* d_in, const int* in_sizes, int n_in,
                              void* d_out, int out_size, void* d_ws, size_t ws_size,
                              hipStream_t stream) {
  const float* q    = (const float*)d_in[0];
  const float* k    = (const float*)d_in[1];
  const float* v    = (const float*)d_in[2];
  const float* rel  = (const float*)d_in[3];
  const int*   mask = (const int*)d_in[4];
  const float* Wq   = (const float*)d_in[5];
  const float* bq   = (const float*)d_in[6];
  const float* Wk   = (const float*)d_in[7];
  const float* bk   = (const float*)d_in[8];
  const float* Wv   = (const float*)d_in[9];
  const float* bv   = (const float*)d_in[10];
  const float* Wo   = (const float*)d_in[11];
  const float* bo   = (const float*)d_in[12];
  float* out = (float*)d_out;

  char* ws = (char*)d_ws;
  float*    qh  = (float*)(ws);                          // 16.78 MB fp32 [b][h][l][d]
  ushort_t* khb = (ushort_t*)(ws + 16777216);            // 8.39 MB bf16 [b][h][r][d]
  ushort_t* vT  = (ushort_t*)(ws + 16777216 + 8388608);  // 8.39 MB bf16 [b][h][d][r]
  ushort_t* X   = (ushort_t*)(ws + 33554432);            // 25.17 MB: qbf/kbf/vbf then Abig
  ushort_t* Y   = (ushort_t*)(ws + 58720256);            // 6.29 MB: W*bf then Wo split
  ushort_t* qbf = X;
  ushort_t* kbf = X + 4194304;
  ushort_t* vbf = X + 8388608;
  ushort_t* Wqb = Y;
  ushort_t* Wkb = Y + 1048576;
  ushort_t* Wvb = Y + 2097152;

  to_bf16<<<1024, 256, 0, stream>>>(q, qbf, 1048576);
  to_bf16<<<1024, 256, 0, stream>>>(k, kbf, 1048576);
  to_bf16<<<1024, 256, 0, stream>>>(v, vbf, 1048576);
  to_bf16<<<256, 256, 0, stream>>>(Wq, Wqb, 262144);
  to_bf16<<<256, 256, 0, stream>>>(Wk, Wkb, 262144);
  to_bf16<<<256, 256, 0, stream>>>(Wv, Wvb, 262144);

  gemm_qkv<<<768, 256, 0, stream>>>(qbf, kbf, vbf, Wqb, Wkb, Wvb,
                                    bq, bk, bv, qh, khb, vT);

  split3_bf16<<<1024, 256, 0, stream>>>(Wo, Y, 1048576);

  attn_mfma<<<512, 256, 0, stream>>>(qh, khb, vT, rel, mask, X);

  gemm_out<<<256, 256, 0, stream>>>(X, Y, bo, out);
}